// Round 1
// baseline (727.607 us; speedup 1.0000x reference)
//
#include <hip/hip_runtime.h>
#include <stdint.h>

// ---------------------------------------------------------------------------
// AttentionBlock fused pipeline for MI355X (gfx950)
//   B=4, C=256, H=W=64 (N=4096 tokens), 32 groups, cond_dim=512
// Pipeline: prep -> gn_stats -> gn_apply(+transpose) -> qkv gemm -> flash attn
//           -> proj gemm (+bias+residual)
// All heavy GEMMs in bf16 MFMA (v_mfma_f32_32x32x16_bf16).
// Workspace map (bytes):
//   sb      f32 [4][512]        @ 0        (8192)
//   stats   f32 [128][2]        @ 8192     (1024)
//   qkvwT   bf16[768][256]      @ 16384    (393216)
//   projwT  bf16[256][256]      @ 409600   (131072)
//   ht      bf16[4][4096][256]  @ 540672   (8388608)   (reused as o_buf)
//   q_buf   bf16[4][4096][256]  @ 8929280  (8388608)
//   k_buf   bf16[4][4096][256]  @ 17317888 (8388608)
//   vt_buf  bf16[4][256][4096]  @ 25706496 (8388608)
//   total ~32.6 MB
// ---------------------------------------------------------------------------

#define AS1 __attribute__((address_space(1)))
#define AS3 __attribute__((address_space(3)))

typedef __attribute__((ext_vector_type(8))) short bf16x8;
typedef __attribute__((ext_vector_type(16))) float f32x16;

static __device__ __forceinline__ unsigned short bf16r(float x) {
  union { float f; unsigned u; } v; v.f = x;
  return (unsigned short)((v.u + 0x7fffu + ((v.u >> 16) & 1u)) >> 16);
}
static __device__ __forceinline__ unsigned bf16pack(float lo, float hi) {
  union { float f; unsigned u; } a, b; a.f = lo; b.f = hi;
  unsigned ua = a.u + 0x7fffu + ((a.u >> 16) & 1u);
  unsigned ub = b.u + 0x7fffu + ((b.u >> 16) & 1u);
  return (ua >> 16) | (ub & 0xffff0000u);
}
static __device__ __forceinline__ void gload16(const void* g, void* lds_uniform) {
  __builtin_amdgcn_global_load_lds((const AS1 unsigned*)g, (AS3 unsigned*)lds_uniform,
                                   16, 0, 0);
}
static __device__ __forceinline__ f32x16 mfma_bf16(bf16x8 a, bf16x8 b, f32x16 c) {
  return __builtin_amdgcn_mfma_f32_32x32x16_bf16(a, b, c, 0, 0, 0);
}

// ---------------------------------------------------------------------------
// prep: weight transposes (bf16) + sb = cond @ lin_w + lin_b
// grid 1025 x 256
__global__ __launch_bounds__(256) void prep_kernel(
    const float* __restrict__ qkv_w, const float* __restrict__ proj_w,
    const float* __restrict__ cond, const float* __restrict__ lin_w,
    const float* __restrict__ lin_b,
    unsigned short* __restrict__ qkvwT, unsigned short* __restrict__ projwT,
    float* __restrict__ sb) {
  int bid = blockIdx.x, t = threadIdx.x;
  if (bid < 768) {
    int j = bid;                       // qkvwT[j][c] = qkv_w[c][j]
    qkvwT[j * 256 + t] = bf16r(qkv_w[t * 768 + j]);
  } else if (bid < 1024) {
    int j = bid - 768;                 // projwT[j][c] = proj_w[c][j]
    projwT[j * 256 + t] = bf16r(proj_w[t * 256 + j]);
  } else {
    for (int o = t * 8; o < t * 8 + 8; ++o) {   // 2048 outputs
      int b = o >> 9, j = o & 511;
      float acc = lin_b[j];
      const float* cp = cond + b * 512;
      for (int kk = 0; kk < 512; ++kk) acc += cp[kk] * lin_w[kk * 512 + j];
      sb[o] = acc;
    }
  }
}

// ---------------------------------------------------------------------------
// gn_stats: per (b,g) mean/rstd over 8*4096 contiguous f32. grid 128 x 256
__global__ __launch_bounds__(256) void gn_stats_kernel(
    const float* __restrict__ x, float* __restrict__ stats) {
  int bg = blockIdx.x;
  const float* p = x + (size_t)bg * 32768;
  float s = 0.f, ss = 0.f;
  for (int k = 0; k < 32; ++k) {
    int i = threadIdx.x * 4 + k * 1024;
    float4 v = *(const float4*)(p + i);
    s += v.x + v.y + v.z + v.w;
    ss += v.x * v.x + v.y * v.y + v.z * v.z + v.w * v.w;
  }
#pragma unroll
  for (int off = 1; off < 64; off <<= 1) {
    s += __shfl_xor(s, off, 64);
    ss += __shfl_xor(ss, off, 64);
  }
  __shared__ float red[8];
  if ((threadIdx.x & 63) == 0) {
    red[(threadIdx.x >> 6) * 2] = s;
    red[(threadIdx.x >> 6) * 2 + 1] = ss;
  }
  __syncthreads();
  if (threadIdx.x == 0) {
    float S = 0.f, SS = 0.f;
#pragma unroll
    for (int i = 0; i < 4; ++i) { S += red[i * 2]; SS += red[i * 2 + 1]; }
    float mean = S * (1.f / 32768.f);
    float var = SS * (1.f / 32768.f) - mean * mean;
    stats[bg * 2] = mean;
    stats[bg * 2 + 1] = rsqrtf(var + 1e-5f);
  }
}

// ---------------------------------------------------------------------------
// gn_apply: h = (x-mean)*rstd*(1+scale)+bias, transpose [C][N]->[N][C] bf16.
// grid 1024 (b,cb,nb) x 256
__global__ __launch_bounds__(256) void gn_apply_kernel(
    const float* __restrict__ x, const float* __restrict__ stats,
    const float* __restrict__ sb, unsigned short* __restrict__ ht) {
  __shared__ __align__(16) unsigned short tile[64][72];
  int b = blockIdx.x >> 8, cb = (blockIdx.x >> 6) & 3, nb = blockIdx.x & 63;
  int t = threadIdx.x;
  int c0 = cb * 64, n0 = nb * 64;
#pragma unroll
  for (int q = 0; q < 4; ++q) {
    int r = q * 16 + (t >> 4);
    int nn = (t & 15) * 4;
    int c = c0 + r;
    float mean = stats[(b * 32 + (c >> 3)) * 2];
    float rstd = stats[(b * 32 + (c >> 3)) * 2 + 1];
    float scl = sb[b * 512 + c], bia = sb[b * 512 + 256 + c];
    float A = rstd * (1.f + scl);
    float Bp = bia - mean * A;
    float4 v = *(const float4*)(x + ((size_t)(b * 256 + c)) * 4096 + n0 + nn);
    ushort4 pk;
    pk.x = bf16r(v.x * A + Bp);
    pk.y = bf16r(v.y * A + Bp);
    pk.z = bf16r(v.z * A + Bp);
    pk.w = bf16r(v.w * A + Bp);
    *(ushort4*)&tile[r][nn] = pk;
  }
  __syncthreads();
#pragma unroll
  for (int q = 0; q < 2; ++q) {
    int n = t & 63, cbase = (t >> 6) * 8 + q * 32;
    bf16x8 outv;
#pragma unroll
    for (int j = 0; j < 8; ++j) outv[j] = (short)tile[cbase + j][n];
    *(bf16x8*)(ht + ((size_t)(b * 4096 + n0 + n)) * 256 + c0 + cbase) = outv;
  }
}

// ---------------------------------------------------------------------------
// QKV GEMM: D[n][j] = ht[n][:] . qkv_w[:][j] + qkv_b[j]   (K=256)
// tile 128(M) x 128(N), BK=64, 4 waves (2x2), each 64x64 via 2x2 of 32x32x16.
// j<256 -> q_buf[N][C]; j<512 -> k_buf[N][C]; else vt_buf[C][N] (transposed).
// grid 768 = 4 * 32 * 6
__global__ __launch_bounds__(256, 2) void qkv_gemm_kernel(
    const unsigned short* __restrict__ ht, const unsigned short* __restrict__ wT,
    const float* __restrict__ qkv_b, unsigned short* __restrict__ q_buf,
    unsigned short* __restrict__ k_buf, unsigned short* __restrict__ vt_buf) {
  __shared__ __align__(16) unsigned short lA[8192];   // [128][64]
  __shared__ __align__(16) unsigned short lB[8192];   // [128][64]
  int bid = blockIdx.x;
  int b = bid / 192, rem = bid % 192;
  int m0 = (rem / 6) * 128, j0 = (rem % 6) * 128;
  int tid = threadIdx.x, lane = tid & 63, w = tid >> 6;
  int wm = w >> 1, wn = w & 1, l31 = lane & 31, lh = lane >> 5;

  f32x16 acc[2][2];
#pragma unroll
  for (int i = 0; i < 2; ++i)
#pragma unroll
    for (int jj = 0; jj < 2; ++jj) acc[i][jj] = (f32x16)0.f;

  const char* htg = (const char*)ht;
  const char* wtg = (const char*)wT;

  for (int ks = 0; ks < 4; ++ks) {
    int k0 = ks * 64;
    if (ks) __syncthreads();
#pragma unroll
    for (int i = 0; i < 4; ++i) {
      int obase = (w * 4 + i) * 1024;
      int o = obase + lane * 16;
      int row = o >> 7, colb = o & 127;
      int sw = (row & 7) << 4;
      gload16(htg + (((size_t)(b * 4096 + m0 + row)) * 256 + k0) * 2 + (colb ^ sw),
              (char*)lA + obase);
      gload16(wtg + (((size_t)(j0 + row)) * 256 + k0) * 2 + (colb ^ sw),
              (char*)lB + obase);
    }
    __syncthreads();
#pragma unroll
    for (int ks16 = 0; ks16 < 4; ++ks16) {
      int colb = ks16 * 32 + lh * 16;
      bf16x8 af[2], bf[2];
#pragma unroll
      for (int ms = 0; ms < 2; ++ms) {
        int row = wm * 64 + ms * 32 + l31;
        af[ms] = *(const bf16x8*)((const char*)lA + row * 128 + (colb ^ ((row & 7) << 4)));
      }
#pragma unroll
      for (int ns = 0; ns < 2; ++ns) {
        int row = wn * 64 + ns * 32 + l31;
        bf[ns] = *(const bf16x8*)((const char*)lB + row * 128 + (colb ^ ((row & 7) << 4)));
      }
#pragma unroll
      for (int ms = 0; ms < 2; ++ms)
#pragma unroll
        for (int ns = 0; ns < 2; ++ns) acc[ms][ns] = mfma_bf16(af[ms], bf[ns], acc[ms][ns]);
    }
  }

#pragma unroll
  for (int ms = 0; ms < 2; ++ms)
#pragma unroll
    for (int ns = 0; ns < 2; ++ns) {
      int j = j0 + wn * 64 + ns * 32 + l31;
      float bias = qkv_b[j];
      if (j < 512) {
        unsigned short* dst = (j < 256) ? q_buf : k_buf;
        int jj = j & 255;
#pragma unroll
        for (int r = 0; r < 16; ++r) {
          int mrow = m0 + wm * 64 + ms * 32 + (r & 3) + 8 * (r >> 2) + 4 * lh;
          dst[((size_t)(b * 4096) + mrow) * 256 + jj] = bf16r(acc[ms][ns][r] + bias);
        }
      } else {
        int d = j - 512;
#pragma unroll
        for (int qd = 0; qd < 4; ++qd) {
          int nbase = m0 + wm * 64 + ms * 32 + 8 * qd + 4 * lh;
          ushort4 pk;
          pk.x = bf16r(acc[ms][ns][qd * 4 + 0] + bias);
          pk.y = bf16r(acc[ms][ns][qd * 4 + 1] + bias);
          pk.z = bf16r(acc[ms][ns][qd * 4 + 2] + bias);
          pk.w = bf16r(acc[ms][ns][qd * 4 + 3] + bias);
          *(ushort4*)(vt_buf + ((size_t)(b * 256) + d) * 4096 + nbase) = pk;
        }
      }
    }
}

// ---------------------------------------------------------------------------
// Flash attention. 256 blocks (b, qt), 4 waves.
// wave w: wq=w&1 (q-rows qt*64+wq*32+..), wk=w>>1 (KV half, 2048 keys).
// Swapped QK^T: S^T = mfma(A=K, B=Q^T): lane owns q-row (lane&31).
// Online softmax base-2 with defer-max; PV: O = mfma(A=P, B=V) using vt.
// Final 2-way KV merge via LDS.
__global__ __launch_bounds__(256, 1) void flash_kernel(
    const unsigned short* __restrict__ qb, const unsigned short* __restrict__ kb,
    const unsigned short* __restrict__ vtb, unsigned short* __restrict__ ob) {
  __shared__ __align__(16) char lds[131072];  // 2 pairs x (K 32KB + V 32KB)
  int bid = blockIdx.x;
  int b = bid >> 6, qt = bid & 63;
  int tid = threadIdx.x, lane = tid & 63, w = tid >> 6;
  int wq = w & 1, wk = w >> 1;
  int l31 = lane & 31, lh = lane >> 5;
  const size_t bq = (size_t)b * 4096;
  const int qrow = qt * 64 + wq * 32 + l31;

  // Q fragments (B-operand layout): qf[f][j] = Q[qrow][f*16 + lh*8 + j]
  bf16x8 qf[16];
  const unsigned short* qp = qb + (bq + qrow) * 256;
#pragma unroll
  for (int f = 0; f < 16; ++f) qf[f] = *(const bf16x8*)(qp + f * 16 + lh * 8);

  f32x16 oacc[8];
#pragma unroll
  for (int dt = 0; dt < 8; ++dt) oacc[dt] = (f32x16)0.f;
  float m = -1e30f, l = 0.f;

  char* kbase = lds + wk * 65536;
  char* vbase = kbase + 32768;
  const char* kg = (const char*)(kb + (bq + (size_t)wk * 2048) * 256);
  const char* vg = (const char*)(vtb + (size_t)b * 1048576 + (size_t)wk * 2048);
  const float sc = 0.09011168852f;  // log2(e)/16

  for (int it = 0; it < 32; ++it) {
    int key0 = it * 64;
    // stage K[64][256] and Vt[256][64] (pre-swizzled source, linear LDS)
#pragma unroll
    for (int i = 0; i < 16; ++i) {
      int obase = wq * 16384 + i * 1024;
      int o = obase + lane * 16;
      {
        int row = o >> 9, colb = o & 511;
        gload16(kg + (key0 + row) * 512 + (colb ^ ((row & 7) << 4)), kbase + obase);
      }
      {
        int rd = o >> 7, cb2 = o & 127;
        gload16(vg + (size_t)rd * 8192 + key0 * 2 + (cb2 ^ ((rd & 7) << 4)),
                vbase + obase);
      }
    }
    __syncthreads();

    // S^T tiles (2 x 32 keys)
    f32x16 sa[2];
#pragma unroll
    for (int t2 = 0; t2 < 2; ++t2) sa[t2] = (f32x16)0.f;
#pragma unroll
    for (int cc = 0; cc < 16; ++cc) {
#pragma unroll
      for (int t2 = 0; t2 < 2; ++t2) {
        int row = t2 * 32 + l31;
        int colb = cc * 32 + lh * 16;
        bf16x8 af = *(const bf16x8*)(kbase + row * 512 + (colb ^ ((row & 7) << 4)));
        sa[t2] = mfma_bf16(af, qf[cc], sa[t2]);
      }
    }

    // online softmax (lane owns q-row l31; partner lane^32 has other 16 keys)
    float pv[32];
    float tm = -1e30f;
#pragma unroll
    for (int t2 = 0; t2 < 2; ++t2)
#pragma unroll
      for (int r = 0; r < 16; ++r) {
        float v = sa[t2][r] * sc;
        pv[t2 * 16 + r] = v;
        tm = fmaxf(tm, v);
      }
    tm = fmaxf(tm, __shfl_xor(tm, 32, 64));
    if (__any(tm > m + 8.0f)) {
      float mn = fmaxf(m, tm);
      float f = exp2f(m - mn);
      m = mn;
      l *= f;
      float fr[16];
#pragma unroll
      for (int r = 0; r < 16; ++r)
        fr[r] = __shfl(f, (r & 3) + 8 * (r >> 2) + 4 * lh, 64);
#pragma unroll
      for (int dt = 0; dt < 8; ++dt)
#pragma unroll
        for (int r = 0; r < 16; ++r) oacc[dt][r] *= fr[r];
    }
    float rs = 0.f;
#pragma unroll
    for (int i = 0; i < 32; ++i) {
      pv[i] = exp2f(pv[i] - m);
      rs += pv[i];
    }
    rs += __shfl_xor(rs, 32, 64);
    l += rs;

    // P -> A-fragments (bf16 pack + half swap)
    unsigned pk[16], px[16];
#pragma unroll
    for (int q = 0; q < 16; ++q) pk[q] = bf16pack(pv[2 * q], pv[2 * q + 1]);
#pragma unroll
    for (int q = 0; q < 16; ++q) px[q] = (unsigned)__shfl_xor((int)pk[q], 32, 64);
    bf16x8 pa[4];
#pragma unroll
    for (int t2 = 0; t2 < 2; ++t2)
#pragma unroll
      for (int kk = 0; kk < 2; ++kk) {
        int L = t2 * 8 + kk * 4;
        union { unsigned u[4]; bf16x8 v; } fr;
        if (lh == 0) {
          fr.u[0] = pk[L]; fr.u[1] = pk[L + 1]; fr.u[2] = px[L]; fr.u[3] = px[L + 1];
        } else {
          fr.u[0] = px[L + 2]; fr.u[1] = px[L + 3]; fr.u[2] = pk[L + 2]; fr.u[3] = pk[L + 3];
        }
        pa[t2 * 2 + kk] = fr.v;
      }

    // PV: O += P . V   (B-frags from transposed V in LDS)
#pragma unroll
    for (int dt = 0; dt < 8; ++dt) {
      int rowd = dt * 32 + l31;
      int sw = (rowd & 7) << 4;
#pragma unroll
      for (int t2 = 0; t2 < 2; ++t2)
#pragma unroll
        for (int kk = 0; kk < 2; ++kk) {
          int colb = t2 * 64 + kk * 32 + lh * 16;
          bf16x8 vf = *(const bf16x8*)(vbase + rowd * 128 + (colb ^ sw));
          oacc[dt] = mfma_bf16(pa[t2 * 2 + kk], vf, oacc[dt]);
        }
    }
    __syncthreads();
  }

  // merge the two KV halves (waves w and w^2 share q-rows)
  float* red = (float*)lds;
  if (lane < 32) {
    red[w * 32 + l31] = m;
    red[128 + w * 32 + l31] = l;
  }
  __syncthreads();
  int pw = w ^ 2;
  float m2 = red[pw * 32 + l31], l2 = red[128 + pw * 32 + l31];
  float M = fmaxf(m, m2);
  float fa = exp2f(m - M), fb = exp2f(m2 - M);
  float denom = fa * l + fb * l2;
  float coef = fa / denom;
  float cr[16];
#pragma unroll
  for (int r = 0; r < 16; ++r)
    cr[r] = __shfl(coef, (r & 3) + 8 * (r >> 2) + 4 * lh, 64);
#pragma unroll
  for (int dt = 0; dt < 8; ++dt)
#pragma unroll
    for (int r = 0; r < 16; ++r) oacc[dt][r] *= cr[r];

  float* obuf = (float*)(lds + 1024);  // [64 rows][256 d]
  __syncthreads();
  if (wk == 0) {
#pragma unroll
    for (int dt = 0; dt < 8; ++dt)
#pragma unroll
      for (int r = 0; r < 16; ++r) {
        int rr = (r & 3) + 8 * (r >> 2) + 4 * lh;
        obuf[(wq * 32 + rr) * 256 + dt * 32 + l31] = oacc[dt][r];
      }
  }
  __syncthreads();
  if (wk == 1) {
#pragma unroll
    for (int dt = 0; dt < 8; ++dt)
#pragma unroll
      for (int r = 0; r < 16; ++r) {
        int rr = (r & 3) + 8 * (r >> 2) + 4 * lh;
        float v = oacc[dt][r] + obuf[(wq * 32 + rr) * 256 + dt * 32 + l31];
        ob[(bq + qt * 64 + wq * 32 + rr) * 256 + dt * 32 + l31] = bf16r(v);
      }
  }
}

// ---------------------------------------------------------------------------
// proj GEMM + bias + residual. G[n][j] = o[n][:].proj_w[:][j]; out[b][j][n] =
// x[b][j][n] + G + proj_b[j].  grid 256 = 4*32*2
__global__ __launch_bounds__(256, 2) void proj_gemm_kernel(
    const unsigned short* __restrict__ obf, const unsigned short* __restrict__ wT,
    const float* __restrict__ proj_b, const float* __restrict__ x,
    float* __restrict__ out) {
  __shared__ __align__(16) unsigned short lA[8192];   // [128][64]
  __shared__ __align__(16) unsigned short lB[8192];   // [128][64]
  int bid = blockIdx.x;
  int b = bid >> 6, mt = (bid >> 1) & 31, nt = bid & 1;
  int m0 = mt * 128, j0 = nt * 128;
  int tid = threadIdx.x, lane = tid & 63, w = tid >> 6;
  int wm = w >> 1, wn = w & 1, l31 = lane & 31, lh = lane >> 5;

  f32x16 acc[2][2];
#pragma unroll
  for (int i = 0; i < 2; ++i)
#pragma unroll
    for (int jj = 0; jj < 2; ++jj) acc[i][jj] = (f32x16)0.f;

  const char* og = (const char*)obf;
  const char* wtg = (const char*)wT;

  for (int ks = 0; ks < 4; ++ks) {
    int k0 = ks * 64;
    if (ks) __syncthreads();
#pragma unroll
    for (int i = 0; i < 4; ++i) {
      int obase = (w * 4 + i) * 1024;
      int o = obase + lane * 16;
      int row = o >> 7, colb = o & 127;
      int sw = (row & 7) << 4;
      gload16(og + (((size_t)(b * 4096 + m0 + row)) * 256 + k0) * 2 + (colb ^ sw),
              (char*)lA + obase);
      gload16(wtg + (((size_t)(j0 + row)) * 256 + k0) * 2 + (colb ^ sw),
              (char*)lB + obase);
    }
    __syncthreads();
#pragma unroll
    for (int ks16 = 0; ks16 < 4; ++ks16) {
      int colb = ks16 * 32 + lh * 16;
      bf16x8 af[2], bf[2];
#pragma unroll
      for (int ms = 0; ms < 2; ++ms) {
        int row = wm * 64 + ms * 32 + l31;
        af[ms] = *(const bf16x8*)((const char*)lA + row * 128 + (colb ^ ((row & 7) << 4)));
      }
#pragma unroll
      for (int ns = 0; ns < 2; ++ns) {
        int row = wn * 64 + ns * 32 + l31;
        bf[ns] = *(const bf16x8*)((const char*)lB + row * 128 + (colb ^ ((row & 7) << 4)));
      }
#pragma unroll
      for (int ms = 0; ms < 2; ++ms)
#pragma unroll
        for (int ns = 0; ns < 2; ++ns) acc[ms][ns] = mfma_bf16(af[ms], bf[ns], acc[ms][ns]);
    }
  }

#pragma unroll
  for (int ms = 0; ms < 2; ++ms)
#pragma unroll
    for (int ns = 0; ns < 2; ++ns) {
      int j = j0 + wn * 64 + ns * 32 + l31;
      float bias = proj_b[j];
#pragma unroll
      for (int qd = 0; qd < 4; ++qd) {
        int nbase = m0 + wm * 64 + ms * 32 + 8 * qd + 4 * lh;
        size_t off = ((size_t)(b * 256) + j) * 4096 + nbase;
        float4 xr = *(const float4*)(x + off);
        float4 o4;
        o4.x = xr.x + bias + acc[ms][ns][qd * 4 + 0];
        o4.y = xr.y + bias + acc[ms][ns][qd * 4 + 1];
        o4.z = xr.z + bias + acc[ms][ns][qd * 4 + 2];
        o4.w = xr.w + bias + acc[ms][ns][qd * 4 + 3];
        *(float4*)(out + off) = o4;
      }
    }
}

// ---------------------------------------------------------------------------
extern "C" void kernel_launch(void* const* d_in, const int* in_sizes, int n_in,
                              void* d_out, int out_size, void* d_ws, size_t ws_size,
                              hipStream_t stream) {
  (void)in_sizes; (void)n_in; (void)out_size; (void)ws_size;
  const float* x      = (const float*)d_in[0];
  const float* cond   = (const float*)d_in[1];
  const float* lin_w  = (const float*)d_in[2];
  const float* lin_b  = (const float*)d_in[3];
  const float* qkv_w  = (const float*)d_in[4];
  const float* qkv_b  = (const float*)d_in[5];
  const float* proj_w = (const float*)d_in[6];
  const float* proj_b = (const float*)d_in[7];
  float* out = (float*)d_out;
  char* ws = (char*)d_ws;

  float* sb              = (float*)(ws + 0);
  float* stats           = (float*)(ws + 8192);
  unsigned short* qkvwT  = (unsigned short*)(ws + 16384);
  unsigned short* projwT = (unsigned short*)(ws + 409600);
  unsigned short* ht     = (unsigned short*)(ws + 540672);
  unsigned short* ob     = ht;  // overlay: ht dead after qkv gemm
  unsigned short* q_buf  = (unsigned short*)(ws + 8929280);
  unsigned short* k_buf  = (unsigned short*)(ws + 17317888);
  unsigned short* vt_buf = (unsigned short*)(ws + 25706496);

  prep_kernel<<<1025, 256, 0, stream>>>(qkv_w, proj_w, cond, lin_w, lin_b,
                                        qkvwT, projwT, sb);
  gn_stats_kernel<<<128, 256, 0, stream>>>(x, stats);
  gn_apply_kernel<<<1024, 256, 0, stream>>>(x, stats, sb, ht);
  qkv_gemm_kernel<<<768, 256, 0, stream>>>(ht, qkvwT, qkv_b, q_buf, k_buf, vt_buf);
  flash_kernel<<<256, 256, 0, stream>>>(q_buf, k_buf, vt_buf, ob);
  proj_gemm_kernel<<<256, 256, 0, stream>>>(ob, projwT, proj_b, x, out);
}

// Round 2
// 275.676 us; speedup vs baseline: 2.6394x; 2.6394x over previous
//
#include <hip/hip_runtime.h>
#include <stdint.h>

// ---------------------------------------------------------------------------
// AttentionBlock fused pipeline for MI355X (gfx950)
//   B=4, C=256, H=W=64 (N=4096 tokens), 32 groups, cond_dim=512
// Pipeline: prep -> gn_stats -> gn_apply(+transpose) -> qkv gemm -> flash attn
//           -> proj gemm (+bias+residual)
// All heavy GEMMs in bf16 MFMA (v_mfma_f32_32x32x16_bf16).
// Workspace map (bytes):
//   sb      f32 [4][512]        @ 0        (8192)
//   stats   f32 [128][2]        @ 8192     (1024)
//   qkvwT   bf16[768][256]      @ 16384    (393216)
//   projwT  bf16[256][256]      @ 409600   (131072)
//   ht      bf16[4][4096][256]  @ 540672   (8388608)   (reused as o_buf)
//   q_buf   bf16[4][4096][256]  @ 8929280  (8388608)
//   k_buf   bf16[4][4096][256]  @ 17317888 (8388608)
//   vt_buf  bf16[4][256][4096]  @ 25706496 (8388608)
//   total ~32.6 MB
// ---------------------------------------------------------------------------

#define AS1 __attribute__((address_space(1)))
#define AS3 __attribute__((address_space(3)))

typedef __attribute__((ext_vector_type(8))) short bf16x8;
typedef __attribute__((ext_vector_type(16))) float f32x16;

static __device__ __forceinline__ unsigned short bf16r(float x) {
  union { float f; unsigned u; } v; v.f = x;
  return (unsigned short)((v.u + 0x7fffu + ((v.u >> 16) & 1u)) >> 16);
}
static __device__ __forceinline__ unsigned bf16pack(float lo, float hi) {
  union { float f; unsigned u; } a, b; a.f = lo; b.f = hi;
  unsigned ua = a.u + 0x7fffu + ((a.u >> 16) & 1u);
  unsigned ub = b.u + 0x7fffu + ((b.u >> 16) & 1u);
  return (ua >> 16) | (ub & 0xffff0000u);
}
static __device__ __forceinline__ void gload16(const void* g, void* lds_uniform) {
  __builtin_amdgcn_global_load_lds((const AS1 unsigned*)g, (AS3 unsigned*)lds_uniform,
                                   16, 0, 0);
}
static __device__ __forceinline__ f32x16 mfma_bf16(bf16x8 a, bf16x8 b, f32x16 c) {
  return __builtin_amdgcn_mfma_f32_32x32x16_bf16(a, b, c, 0, 0, 0);
}

// ---------------------------------------------------------------------------
// prep: weight transposes (bf16, LDS tile transpose) + sb = cond@lin_w + lin_b
// grid 72 x 256:
//   blocks 0..47  : qkv_w [256][768] -> qkvwT [768][256], 64x64 tiles (12 j x 4 c)
//   blocks 48..63 : proj_w [256][256] -> projwT [256][256], 64x64 tiles (4 j x 4 c)
//   blocks 64..71 : sb[b][j] (b = s>>1, j = (s&1)*256 + t), coalesced lin_w cols
__global__ __launch_bounds__(256) void prep_kernel(
    const float* __restrict__ qkv_w, const float* __restrict__ proj_w,
    const float* __restrict__ cond, const float* __restrict__ lin_w,
    const float* __restrict__ lin_b,
    unsigned short* __restrict__ qkvwT, unsigned short* __restrict__ projwT,
    float* __restrict__ sb) {
  int bid = blockIdx.x, t = threadIdx.x;
  if (bid < 64) {
    __shared__ float tile[64][68];   // pad 4 floats: rows 16B-aligned, col reads 2-way alias (free)
    const float* src;
    unsigned short* dst;
    int srcCols, j0, c0;
    if (bid < 48) {
      src = qkv_w; dst = qkvwT; srcCols = 768;
      j0 = (bid >> 2) * 64; c0 = (bid & 3) * 64;
    } else {
      int b2 = bid - 48;
      src = proj_w; dst = projwT; srcCols = 256;
      j0 = (b2 >> 2) * 64; c0 = (b2 & 3) * 64;
    }
    int r = t >> 4, col4 = (t & 15) * 4;
#pragma unroll
    for (int q = 0; q < 4; ++q) {
      float4 v = *(const float4*)(src + (size_t)(c0 + r + q * 16) * srcCols + j0 + col4);
      *(float4*)&tile[r + q * 16][col4] = v;
    }
    __syncthreads();
    int jj = t >> 2, cc = (t & 3) * 16;
    union { unsigned short us[16]; bf16x8 v[2]; } o;
#pragma unroll
    for (int i = 0; i < 16; ++i) o.us[i] = bf16r(tile[cc + i][jj]);
    unsigned short* dp = dst + (size_t)(j0 + jj) * 256 + c0 + cc;
    *(bf16x8*)dp = o.v[0];
    *(bf16x8*)(dp + 8) = o.v[1];
  } else {
    int s = bid - 64;
    int b = s >> 1, j = (s & 1) * 256 + t;
    float acc = lin_b[j];
    const float* cp = cond + b * 512;
    const float* wp = lin_w + j;
#pragma unroll 8
    for (int kk = 0; kk < 512; ++kk) acc += cp[kk] * wp[(size_t)kk * 512];
    sb[b * 512 + j] = acc;
  }
}

// ---------------------------------------------------------------------------
// gn_stats: per (b,g) mean/rstd over 8*4096 contiguous f32. grid 128 x 256
__global__ __launch_bounds__(256) void gn_stats_kernel(
    const float* __restrict__ x, float* __restrict__ stats) {
  int bg = blockIdx.x;
  const float* p = x + (size_t)bg * 32768;
  float s = 0.f, ss = 0.f;
  for (int k = 0; k < 32; ++k) {
    int i = threadIdx.x * 4 + k * 1024;
    float4 v = *(const float4*)(p + i);
    s += v.x + v.y + v.z + v.w;
    ss += v.x * v.x + v.y * v.y + v.z * v.z + v.w * v.w;
  }
#pragma unroll
  for (int off = 1; off < 64; off <<= 1) {
    s += __shfl_xor(s, off, 64);
    ss += __shfl_xor(ss, off, 64);
  }
  __shared__ float red[8];
  if ((threadIdx.x & 63) == 0) {
    red[(threadIdx.x >> 6) * 2] = s;
    red[(threadIdx.x >> 6) * 2 + 1] = ss;
  }
  __syncthreads();
  if (threadIdx.x == 0) {
    float S = 0.f, SS = 0.f;
#pragma unroll
    for (int i = 0; i < 4; ++i) { S += red[i * 2]; SS += red[i * 2 + 1]; }
    float mean = S * (1.f / 32768.f);
    float var = SS * (1.f / 32768.f) - mean * mean;
    stats[bg * 2] = mean;
    stats[bg * 2 + 1] = rsqrtf(var + 1e-5f);
  }
}

// ---------------------------------------------------------------------------
// gn_apply: h = (x-mean)*rstd*(1+scale)+bias, transpose [C][N]->[N][C] bf16.
// grid 1024 (b,cb,nb) x 256
__global__ __launch_bounds__(256) void gn_apply_kernel(
    const float* __restrict__ x, const float* __restrict__ stats,
    const float* __restrict__ sb, unsigned short* __restrict__ ht) {
  __shared__ __align__(16) unsigned short tile[64][72];
  int b = blockIdx.x >> 8, cb = (blockIdx.x >> 6) & 3, nb = blockIdx.x & 63;
  int t = threadIdx.x;
  int c0 = cb * 64, n0 = nb * 64;
#pragma unroll
  for (int q = 0; q < 4; ++q) {
    int r = q * 16 + (t >> 4);
    int nn = (t & 15) * 4;
    int c = c0 + r;
    float mean = stats[(b * 32 + (c >> 3)) * 2];
    float rstd = stats[(b * 32 + (c >> 3)) * 2 + 1];
    float scl = sb[b * 512 + c], bia = sb[b * 512 + 256 + c];
    float A = rstd * (1.f + scl);
    float Bp = bia - mean * A;
    float4 v = *(const float4*)(x + ((size_t)(b * 256 + c)) * 4096 + n0 + nn);
    ushort4 pk;
    pk.x = bf16r(v.x * A + Bp);
    pk.y = bf16r(v.y * A + Bp);
    pk.z = bf16r(v.z * A + Bp);
    pk.w = bf16r(v.w * A + Bp);
    *(ushort4*)&tile[r][nn] = pk;
  }
  __syncthreads();
#pragma unroll
  for (int q = 0; q < 2; ++q) {
    int n = t & 63, cbase = (t >> 6) * 8 + q * 32;
    bf16x8 outv;
#pragma unroll
    for (int j = 0; j < 8; ++j) outv[j] = (short)tile[cbase + j][n];
    *(bf16x8*)(ht + ((size_t)(b * 4096 + n0 + n)) * 256 + c0 + cbase) = outv;
  }
}

// ---------------------------------------------------------------------------
// QKV GEMM: D[n][j] = ht[n][:] . qkv_w[:][j] + qkv_b[j]   (K=256)
// tile 128(M) x 128(N), BK=64, 4 waves (2x2), each 64x64 via 2x2 of 32x32x16.
// j<256 -> q_buf[N][C]; j<512 -> k_buf[N][C]; else vt_buf[C][N] (transposed).
// grid 768 = 4 * 32 * 6
__global__ __launch_bounds__(256, 2) void qkv_gemm_kernel(
    const unsigned short* __restrict__ ht, const unsigned short* __restrict__ wT,
    const float* __restrict__ qkv_b, unsigned short* __restrict__ q_buf,
    unsigned short* __restrict__ k_buf, unsigned short* __restrict__ vt_buf) {
  __shared__ __align__(16) unsigned short lA[8192];   // [128][64]
  __shared__ __align__(16) unsigned short lB[8192];   // [128][64]
  int bid = blockIdx.x;
  int b = bid / 192, rem = bid % 192;
  int m0 = (rem / 6) * 128, j0 = (rem % 6) * 128;
  int tid = threadIdx.x, lane = tid & 63, w = tid >> 6;
  int wm = w >> 1, wn = w & 1, l31 = lane & 31, lh = lane >> 5;

  f32x16 acc[2][2];
#pragma unroll
  for (int i = 0; i < 2; ++i)
#pragma unroll
    for (int jj = 0; jj < 2; ++jj) acc[i][jj] = (f32x16)0.f;

  const char* htg = (const char*)ht;
  const char* wtg = (const char*)wT;

  for (int ks = 0; ks < 4; ++ks) {
    int k0 = ks * 64;
    if (ks) __syncthreads();
#pragma unroll
    for (int i = 0; i < 4; ++i) {
      int obase = (w * 4 + i) * 1024;
      int o = obase + lane * 16;
      int row = o >> 7, colb = o & 127;
      int sw = (row & 7) << 4;
      gload16(htg + (((size_t)(b * 4096 + m0 + row)) * 256 + k0) * 2 + (colb ^ sw),
              (char*)lA + obase);
      gload16(wtg + (((size_t)(j0 + row)) * 256 + k0) * 2 + (colb ^ sw),
              (char*)lB + obase);
    }
    __syncthreads();
#pragma unroll
    for (int ks16 = 0; ks16 < 4; ++ks16) {
      int colb = ks16 * 32 + lh * 16;
      bf16x8 af[2], bf[2];
#pragma unroll
      for (int ms = 0; ms < 2; ++ms) {
        int row = wm * 64 + ms * 32 + l31;
        af[ms] = *(const bf16x8*)((const char*)lA + row * 128 + (colb ^ ((row & 7) << 4)));
      }
#pragma unroll
      for (int ns = 0; ns < 2; ++ns) {
        int row = wn * 64 + ns * 32 + l31;
        bf[ns] = *(const bf16x8*)((const char*)lB + row * 128 + (colb ^ ((row & 7) << 4)));
      }
#pragma unroll
      for (int ms = 0; ms < 2; ++ms)
#pragma unroll
        for (int ns = 0; ns < 2; ++ns) acc[ms][ns] = mfma_bf16(af[ms], bf[ns], acc[ms][ns]);
    }
  }

#pragma unroll
  for (int ms = 0; ms < 2; ++ms)
#pragma unroll
    for (int ns = 0; ns < 2; ++ns) {
      int j = j0 + wn * 64 + ns * 32 + l31;
      float bias = qkv_b[j];
      if (j < 512) {
        unsigned short* dst = (j < 256) ? q_buf : k_buf;
        int jj = j & 255;
#pragma unroll
        for (int r = 0; r < 16; ++r) {
          int mrow = m0 + wm * 64 + ms * 32 + (r & 3) + 8 * (r >> 2) + 4 * lh;
          dst[((size_t)(b * 4096) + mrow) * 256 + jj] = bf16r(acc[ms][ns][r] + bias);
        }
      } else {
        int d = j - 512;
#pragma unroll
        for (int qd = 0; qd < 4; ++qd) {
          int nbase = m0 + wm * 64 + ms * 32 + 8 * qd + 4 * lh;
          ushort4 pk;
          pk.x = bf16r(acc[ms][ns][qd * 4 + 0] + bias);
          pk.y = bf16r(acc[ms][ns][qd * 4 + 1] + bias);
          pk.z = bf16r(acc[ms][ns][qd * 4 + 2] + bias);
          pk.w = bf16r(acc[ms][ns][qd * 4 + 3] + bias);
          *(ushort4*)(vt_buf + ((size_t)(b * 256) + d) * 4096 + nbase) = pk;
        }
      }
    }
}

// ---------------------------------------------------------------------------
// Flash attention. 256 blocks (b, qt), 4 waves.
// wave w: wq=w&1 (q-rows qt*64+wq*32+..), wk=w>>1 (KV half, 2048 keys).
// Swapped QK^T: S^T = mfma(A=K, B=Q^T): lane owns q-row (lane&31).
// Online softmax base-2 with defer-max; PV: O = mfma(A=P, B=V) using vt.
// Final 2-way KV merge via LDS.
__global__ __launch_bounds__(256, 1) void flash_kernel(
    const unsigned short* __restrict__ qb, const unsigned short* __restrict__ kb,
    const unsigned short* __restrict__ vtb, unsigned short* __restrict__ ob) {
  __shared__ __align__(16) char lds[131072];  // 2 pairs x (K 32KB + V 32KB)
  int bid = blockIdx.x;
  int b = bid >> 6, qt = bid & 63;
  int tid = threadIdx.x, lane = tid & 63, w = tid >> 6;
  int wq = w & 1, wk = w >> 1;
  int l31 = lane & 31, lh = lane >> 5;
  const size_t bq = (size_t)b * 4096;
  const int qrow = qt * 64 + wq * 32 + l31;

  // Q fragments (B-operand layout): qf[f][j] = Q[qrow][f*16 + lh*8 + j]
  bf16x8 qf[16];
  const unsigned short* qp = qb + (bq + qrow) * 256;
#pragma unroll
  for (int f = 0; f < 16; ++f) qf[f] = *(const bf16x8*)(qp + f * 16 + lh * 8);

  f32x16 oacc[8];
#pragma unroll
  for (int dt = 0; dt < 8; ++dt) oacc[dt] = (f32x16)0.f;
  float m = -1e30f, l = 0.f;

  char* kbase = lds + wk * 65536;
  char* vbase = kbase + 32768;
  const char* kg = (const char*)(kb + (bq + (size_t)wk * 2048) * 256);
  const char* vg = (const char*)(vtb + (size_t)b * 1048576 + (size_t)wk * 2048);
  const float sc = 0.09011168852f;  // log2(e)/16

  for (int it = 0; it < 32; ++it) {
    int key0 = it * 64;
    // stage K[64][256] and Vt[256][64] (pre-swizzled source, linear LDS)
#pragma unroll
    for (int i = 0; i < 16; ++i) {
      int obase = wq * 16384 + i * 1024;
      int o = obase + lane * 16;
      {
        int row = o >> 9, colb = o & 511;
        gload16(kg + (key0 + row) * 512 + (colb ^ ((row & 7) << 4)), kbase + obase);
      }
      {
        int rd = o >> 7, cb2 = o & 127;
        gload16(vg + (size_t)rd * 8192 + key0 * 2 + (cb2 ^ ((rd & 7) << 4)),
                vbase + obase);
      }
    }
    __syncthreads();

    // S^T tiles (2 x 32 keys)
    f32x16 sa[2];
#pragma unroll
    for (int t2 = 0; t2 < 2; ++t2) sa[t2] = (f32x16)0.f;
#pragma unroll
    for (int cc = 0; cc < 16; ++cc) {
#pragma unroll
      for (int t2 = 0; t2 < 2; ++t2) {
        int row = t2 * 32 + l31;
        int colb = cc * 32 + lh * 16;
        bf16x8 af = *(const bf16x8*)(kbase + row * 512 + (colb ^ ((row & 7) << 4)));
        sa[t2] = mfma_bf16(af, qf[cc], sa[t2]);
      }
    }

    // online softmax (lane owns q-row l31; partner lane^32 has other 16 keys)
    float pv[32];
    float tm = -1e30f;
#pragma unroll
    for (int t2 = 0; t2 < 2; ++t2)
#pragma unroll
      for (int r = 0; r < 16; ++r) {
        float v = sa[t2][r] * sc;
        pv[t2 * 16 + r] = v;
        tm = fmaxf(tm, v);
      }
    tm = fmaxf(tm, __shfl_xor(tm, 32, 64));
    if (__any(tm > m + 8.0f)) {
      float mn = fmaxf(m, tm);
      float f = exp2f(m - mn);
      m = mn;
      l *= f;
      float fr[16];
#pragma unroll
      for (int r = 0; r < 16; ++r)
        fr[r] = __shfl(f, (r & 3) + 8 * (r >> 2) + 4 * lh, 64);
#pragma unroll
      for (int dt = 0; dt < 8; ++dt)
#pragma unroll
        for (int r = 0; r < 16; ++r) oacc[dt][r] *= fr[r];
    }
    float rs = 0.f;
#pragma unroll
    for (int i = 0; i < 32; ++i) {
      pv[i] = exp2f(pv[i] - m);
      rs += pv[i];
    }
    rs += __shfl_xor(rs, 32, 64);
    l += rs;

    // P -> A-fragments (bf16 pack + half swap)
    unsigned pk[16], px[16];
#pragma unroll
    for (int q = 0; q < 16; ++q) pk[q] = bf16pack(pv[2 * q], pv[2 * q + 1]);
#pragma unroll
    for (int q = 0; q < 16; ++q) px[q] = (unsigned)__shfl_xor((int)pk[q], 32, 64);
    bf16x8 pa[4];
#pragma unroll
    for (int t2 = 0; t2 < 2; ++t2)
#pragma unroll
      for (int kk = 0; kk < 2; ++kk) {
        int L = t2 * 8 + kk * 4;
        union { unsigned u[4]; bf16x8 v; } fr;
        if (lh == 0) {
          fr.u[0] = pk[L]; fr.u[1] = pk[L + 1]; fr.u[2] = px[L]; fr.u[3] = px[L + 1];
        } else {
          fr.u[0] = px[L + 2]; fr.u[1] = px[L + 3]; fr.u[2] = pk[L + 2]; fr.u[3] = pk[L + 3];
        }
        pa[t2 * 2 + kk] = fr.v;
      }

    // PV: O += P . V   (B-frags from transposed V in LDS)
#pragma unroll
    for (int dt = 0; dt < 8; ++dt) {
      int rowd = dt * 32 + l31;
      int sw = (rowd & 7) << 4;
#pragma unroll
      for (int t2 = 0; t2 < 2; ++t2)
#pragma unroll
        for (int kk = 0; kk < 2; ++kk) {
          int colb = t2 * 64 + kk * 32 + lh * 16;
          bf16x8 vf = *(const bf16x8*)(vbase + rowd * 128 + (colb ^ sw));
          oacc[dt] = mfma_bf16(pa[t2 * 2 + kk], vf, oacc[dt]);
        }
    }
    __syncthreads();
  }

  // merge the two KV halves (waves w and w^2 share q-rows)
  float* red = (float*)lds;
  if (lane < 32) {
    red[w * 32 + l31] = m;
    red[128 + w * 32 + l31] = l;
  }
  __syncthreads();
  int pw = w ^ 2;
  float m2 = red[pw * 32 + l31], l2 = red[128 + pw * 32 + l31];
  float M = fmaxf(m, m2);
  float fa = exp2f(m - M), fb = exp2f(m2 - M);
  float denom = fa * l + fb * l2;
  float coef = fa / denom;
  float cr[16];
#pragma unroll
  for (int r = 0; r < 16; ++r)
    cr[r] = __shfl(coef, (r & 3) + 8 * (r >> 2) + 4 * lh, 64);
#pragma unroll
  for (int dt = 0; dt < 8; ++dt)
#pragma unroll
    for (int r = 0; r < 16; ++r) oacc[dt][r] *= cr[r];

  float* obuf = (float*)(lds + 1024);  // [64 rows][256 d]
  __syncthreads();
  if (wk == 0) {
#pragma unroll
    for (int dt = 0; dt < 8; ++dt)
#pragma unroll
      for (int r = 0; r < 16; ++r) {
        int rr = (r & 3) + 8 * (r >> 2) + 4 * lh;
        obuf[(wq * 32 + rr) * 256 + dt * 32 + l31] = oacc[dt][r];
      }
  }
  __syncthreads();
  if (wk == 1) {
#pragma unroll
    for (int dt = 0; dt < 8; ++dt)
#pragma unroll
      for (int r = 0; r < 16; ++r) {
        int rr = (r & 3) + 8 * (r >> 2) + 4 * lh;
        float v = oacc[dt][r] + obuf[(wq * 32 + rr) * 256 + dt * 32 + l31];
        ob[(bq + qt * 64 + wq * 32 + rr) * 256 + dt * 32 + l31] = bf16r(v);
      }
  }
}

// ---------------------------------------------------------------------------
// proj GEMM + bias + residual. G[n][j] = o[n][:].proj_w[:][j]; out[b][j][n] =
// x[b][j][n] + G + proj_b[j].  grid 256 = 4*32*2
__global__ __launch_bounds__(256, 2) void proj_gemm_kernel(
    const unsigned short* __restrict__ obf, const unsigned short* __restrict__ wT,
    const float* __restrict__ proj_b, const float* __restrict__ x,
    float* __restrict__ out) {
  __shared__ __align__(16) unsigned short lA[8192];   // [128][64]
  __shared__ __align__(16) unsigned short lB[8192];   // [128][64]
  int bid = blockIdx.x;
  int b = bid >> 6, mt = (bid >> 1) & 31, nt = bid & 1;
  int m0 = mt * 128, j0 = nt * 128;
  int tid = threadIdx.x, lane = tid & 63, w = tid >> 6;
  int wm = w >> 1, wn = w & 1, l31 = lane & 31, lh = lane >> 5;

  f32x16 acc[2][2];
#pragma unroll
  for (int i = 0; i < 2; ++i)
#pragma unroll
    for (int jj = 0; jj < 2; ++jj) acc[i][jj] = (f32x16)0.f;

  const char* og = (const char*)obf;
  const char* wtg = (const char*)wT;

  for (int ks = 0; ks < 4; ++ks) {
    int k0 = ks * 64;
    if (ks) __syncthreads();
#pragma unroll
    for (int i = 0; i < 4; ++i) {
      int obase = (w * 4 + i) * 1024;
      int o = obase + lane * 16;
      int row = o >> 7, colb = o & 127;
      int sw = (row & 7) << 4;
      gload16(og + (((size_t)(b * 4096 + m0 + row)) * 256 + k0) * 2 + (colb ^ sw),
              (char*)lA + obase);
      gload16(wtg + (((size_t)(j0 + row)) * 256 + k0) * 2 + (colb ^ sw),
              (char*)lB + obase);
    }
    __syncthreads();
#pragma unroll
    for (int ks16 = 0; ks16 < 4; ++ks16) {
      int colb = ks16 * 32 + lh * 16;
      bf16x8 af[2], bf[2];
#pragma unroll
      for (int ms = 0; ms < 2; ++ms) {
        int row = wm * 64 + ms * 32 + l31;
        af[ms] = *(const bf16x8*)((const char*)lA + row * 128 + (colb ^ ((row & 7) << 4)));
      }
#pragma unroll
      for (int ns = 0; ns < 2; ++ns) {
        int row = wn * 64 + ns * 32 + l31;
        bf[ns] = *(const bf16x8*)((const char*)lB + row * 128 + (colb ^ ((row & 7) << 4)));
      }
#pragma unroll
      for (int ms = 0; ms < 2; ++ms)
#pragma unroll
        for (int ns = 0; ns < 2; ++ns) acc[ms][ns] = mfma_bf16(af[ms], bf[ns], acc[ms][ns]);
    }
  }

#pragma unroll
  for (int ms = 0; ms < 2; ++ms)
#pragma unroll
    for (int ns = 0; ns < 2; ++ns) {
      int j = j0 + wn * 64 + ns * 32 + l31;
      float bias = proj_b[j];
#pragma unroll
      for (int qd = 0; qd < 4; ++qd) {
        int nbase = m0 + wm * 64 + ms * 32 + 8 * qd + 4 * lh;
        size_t off = ((size_t)(b * 256) + j) * 4096 + nbase;
        float4 xr = *(const float4*)(x + off);
        float4 o4;
        o4.x = xr.x + bias + acc[ms][ns][qd * 4 + 0];
        o4.y = xr.y + bias + acc[ms][ns][qd * 4 + 1];
        o4.z = xr.z + bias + acc[ms][ns][qd * 4 + 2];
        o4.w = xr.w + bias + acc[ms][ns][qd * 4 + 3];
        *(float4*)(out + off) = o4;
      }
    }
}

// ---------------------------------------------------------------------------
extern "C" void kernel_launch(void* const* d_in, const int* in_sizes, int n_in,
                              void* d_out, int out_size, void* d_ws, size_t ws_size,
                              hipStream_t stream) {
  (void)in_sizes; (void)n_in; (void)out_size; (void)ws_size;
  const float* x      = (const float*)d_in[0];
  const float* cond   = (const float*)d_in[1];
  const float* lin_w  = (const float*)d_in[2];
  const float* lin_b  = (const float*)d_in[3];
  const float* qkv_w  = (const float*)d_in[4];
  const float* qkv_b  = (const float*)d_in[5];
  const float* proj_w = (const float*)d_in[6];
  const float* proj_b = (const float*)d_in[7];
  float* out = (float*)d_out;
  char* ws = (char*)d_ws;

  float* sb              = (float*)(ws + 0);
  float* stats           = (float*)(ws + 8192);
  unsigned short* qkvwT  = (unsigned short*)(ws + 16384);
  unsigned short* projwT = (unsigned short*)(ws + 409600);
  unsigned short* ht     = (unsigned short*)(ws + 540672);
  unsigned short* ob     = ht;  // overlay: ht dead after qkv gemm
  unsigned short* q_buf  = (unsigned short*)(ws + 8929280);
  unsigned short* k_buf  = (unsigned short*)(ws + 17317888);
  unsigned short* vt_buf = (unsigned short*)(ws + 25706496);

  prep_kernel<<<72, 256, 0, stream>>>(qkv_w, proj_w, cond, lin_w, lin_b,
                                      qkvwT, projwT, sb);
  gn_stats_kernel<<<128, 256, 0, stream>>>(x, stats);
  gn_apply_kernel<<<1024, 256, 0, stream>>>(x, stats, sb, ht);
  qkv_gemm_kernel<<<768, 256, 0, stream>>>(ht, qkvwT, qkv_b, q_buf, k_buf, vt_buf);
  flash_kernel<<<256, 256, 0, stream>>>(q_buf, k_buf, vt_buf, ob);
  proj_gemm_kernel<<<256, 256, 0, stream>>>(ob, projwT, proj_b, x, out);
}